// Round 6
// baseline (695.228 us; speedup 1.0000x reference)
//
#include <hip/hip_runtime.h>

#define CH    128
#define IMG   56
#define HWSZ  3136
#define NPIX  200704        // 64*3136
#define WELEMS 147456       // 128*128*9
#define BNEPS 1e-5f
#define IMGB  401408        // bytes per image, u8 NHWC (3136*128)

// ---- d_out layout (102,760,448 B total, fp32 output) ----
//  q1 u8 NHWC : [0, 25,690,112)
//  y  i16 NHWC: [25,690,112, 77,070,336)
//  q2 u8 NHWC : [77,070,336, 102,760,448)
//  wq1 f16    : [77,070,336, 77,365,248)   (dead before q2 written)
#define YOFF   25690112u
#define Q2OFF  77070336u
// ---- d_ws layout (700,928 B used) ----
//  sm: alpha@0, stats1@256, stats2@1280, bnp1@2304, bnp2@3328  (4,608 B)
//  wq2 f16: [4,608, 299,520)
//  q2 image-63 copy: [299,520, 700,928)

typedef _Float16 f16;
typedef _Float16 f16x8 __attribute__((ext_vector_type(8)));
typedef short    short8 __attribute__((ext_vector_type(8)));
typedef float    f32x4 __attribute__((ext_vector_type(4)));

// ---------------- weight absmax (fp32 inputs) ----------------
__global__ void k_wmax(const float* __restrict__ w1, const float* __restrict__ w2,
                       unsigned* __restrict__ alpha_bits) {
  int idx = blockIdx.x * 256 + threadIdx.x;
  float m1 = 0.f, m2 = 0.f;
  for (int i = idx; i < WELEMS; i += gridDim.x * 256) {
    m1 = fmaxf(m1, fabsf(w1[i]));
    m2 = fmaxf(m2, fabsf(w2[i]));
  }
#pragma unroll
  for (int off = 32; off > 0; off >>= 1) {
    m1 = fmaxf(m1, __shfl_xor(m1, off));
    m2 = fmaxf(m2, __shfl_xor(m2, off));
  }
  __shared__ float s1[4], s2[4];
  int wave = threadIdx.x >> 6;
  if ((threadIdx.x & 63) == 0) { s1[wave] = m1; s2[wave] = m2; }
  __syncthreads();
  if (threadIdx.x == 0) {
    m1 = fmaxf(fmaxf(s1[0], s1[1]), fmaxf(s1[2], s1[3]));
    m2 = fmaxf(fmaxf(s2[0], s2[1]), fmaxf(s2[2], s2[3]));
    atomicMax(&alpha_bits[0], __float_as_uint(m1));  // positive floats: uint order == float order
    atomicMax(&alpha_bits[1], __float_as_uint(m2));
  }
}

// ---------------- weight quantize to integer f16 (-7..7), OIHW -> [kk][co][ci] ----------------
__global__ void k_wquant(const float* __restrict__ w1, const float* __restrict__ w2,
                         const unsigned* __restrict__ alpha_bits,
                         f16* __restrict__ wq1, f16* __restrict__ wq2) {
  int idx = blockIdx.x * 256 + threadIdx.x;     // 0 .. 2*WELEMS-1
  int t = idx >= WELEMS;
  int j = t ? idx - WELEMS : idx;
  int kk  = j >> 14;
  int rem = j & 16383;
  int co = rem >> 7, ci = rem & 127;
  float alpha = __uint_as_float(alpha_bits[t]) + 1e-12f;
  float v  = (t ? w2 : w1)[co * 1152 + ci * 9 + kk];
  float wc = fminf(fmaxf(v / alpha, -1.f), 1.f);
  (t ? wq2 : wq1)[j] = (f16)rintf(wc * 7.f);    // exact small integer
}

// ---------------- act quant to u8 (0..15) + NCHW fp32 -> NHWC u8 ----------------
__global__ void k_actq(const float* __restrict__ x, unsigned char* __restrict__ qx) {
  __shared__ float tile[32][33];
  int n = blockIdx.z, p0 = blockIdx.x * 32, c0 = blockIdx.y * 32;
  int tx = threadIdx.x, ty = threadIdx.y;
  const float* xs = x + ((size_t)n * CH + c0) * HWSZ;
#pragma unroll
  for (int r = 0; r < 4; ++r) {
    int c = ty + r * 8;
    float v = xs[(size_t)c * HWSZ + p0 + tx];     // coalesced along p
    v = fminf(fmaxf(v, 0.f), 1.f);                // also kills NaN
    tile[c][tx] = rintf(v * 15.f);                // RNE == jnp.round
  }
  __syncthreads();
  unsigned char* qs = qx + ((size_t)n * HWSZ + p0) * CH;
#pragma unroll
  for (int r = 0; r < 4; ++r) {
    int pl = ty + r * 8;
    qs[(size_t)pl * CH + c0 + tx] = (unsigned char)tile[tx][pl];
  }
}

// ============ conv macro pieces (u8 acts -> f16, int-f16 weights, exact int math) ============
#define CONV_PROLOGUE                                                            \
  const int tid  = threadIdx.x;                                                  \
  const int wave = tid >> 6, lane = tid & 63;                                    \
  const int quad = lane >> 4, lrow = lane & 15;                                  \
  const int m_off = (wave >> 1) * 64, n_off = (wave & 1) * 64;                   \
  const int p_base = blockIdx.x * 128;                                           \
  int a_r[4], a_cc[4], a_h[4], a_w[4]; long a_base[4];                           \
  _Pragma("unroll")                                                              \
  for (int i = 0; i < 4; ++i) {                                                  \
    int c = tid + i * 256;                                                       \
    int r = c >> 3, cc = (c & 7) * 8;                                            \
    a_r[i] = r; a_cc[i] = cc;                                                    \
    int p = p_base + r;                                                          \
    int n = p / HWSZ, hw = p - n * HWSZ;                                         \
    a_h[i] = hw / IMG; a_w[i] = hw - a_h[i] * IMG;                               \
    a_base[i] = (long)p * CH + cc;                                               \
  }                                                                              \
  f32x4 acc[4][4];                                                               \
  _Pragma("unroll")                                                              \
  for (int mi = 0; mi < 4; ++mi)                                                 \
    _Pragma("unroll")                                                            \
    for (int ni = 0; ni < 4; ++ni) acc[mi][ni] = (f32x4){0.f, 0.f, 0.f, 0.f};

#define CONV_KLOOP(ACT, WQ, AS, BS)                                              \
  for (int kk = 0; kk < 9; ++kk) {                                               \
    const int dh = kk / 3 - 1, dw = kk % 3 - 1;                                  \
    const int doff = (dh * IMG + dw) * CH;                                       \
    for (int ci0 = 0; ci0 < CH; ci0 += 64) {                                     \
      __syncthreads();                                                           \
      _Pragma("unroll")                                                          \
      for (int i = 0; i < 4; ++i) {                                              \
        int sh_ = a_h[i] + dh, sw_ = a_w[i] + dw;                                \
        unsigned lo = 0u, hi = 0u;                                               \
        if ((unsigned)sh_ < (unsigned)IMG && (unsigned)sw_ < (unsigned)IMG) {    \
          uint2 t = *(const uint2*)((ACT) + a_base[i] + doff + ci0);             \
          lo = t.x; hi = t.y;                                                    \
        }                                                                        \
        f16x8 o;                                                                 \
        o[0] = (f16)(float)(lo & 0xFF);  o[1] = (f16)(float)((lo >> 8) & 0xFF);  \
        o[2] = (f16)(float)((lo >> 16) & 0xFF); o[3] = (f16)(float)(lo >> 24);   \
        o[4] = (f16)(float)(hi & 0xFF);  o[5] = (f16)(float)((hi >> 8) & 0xFF);  \
        o[6] = (f16)(float)((hi >> 16) & 0xFF); o[7] = (f16)(float)(hi >> 24);   \
        *(f16x8*)&AS[a_r[i]][a_cc[i]] = o;                                       \
      }                                                                          \
      _Pragma("unroll")                                                          \
      for (int i = 0; i < 4; ++i)                                                \
        *(uint4*)&BS[a_r[i]][a_cc[i]] =                                          \
            *(const uint4*)((WQ) + (size_t)kk * (CH * CH) + a_r[i] * CH + ci0 + a_cc[i]); \
      __syncthreads();                                                           \
      _Pragma("unroll")                                                          \
      for (int ks = 0; ks < 2; ++ks) {                                           \
        const int kof = ks * 32 + quad * 8;                                      \
        f16x8 af[4], bfr[4];                                                     \
        _Pragma("unroll")                                                        \
        for (int mi = 0; mi < 4; ++mi) af[mi]  = *(const f16x8*)&AS[m_off + mi * 16 + lrow][kof]; \
        _Pragma("unroll")                                                        \
        for (int ni = 0; ni < 4; ++ni) bfr[ni] = *(const f16x8*)&BS[n_off + ni * 16 + lrow][kof]; \
        _Pragma("unroll")                                                        \
        for (int mi = 0; mi < 4; ++mi)                                           \
          _Pragma("unroll")                                                      \
          for (int ni = 0; ni < 4; ++ni)                                         \
            acc[mi][ni] = __builtin_amdgcn_mfma_f32_16x16x32_f16(af[mi], bfr[ni], acc[mi][ni], 0, 0, 0); \
      }                                                                          \
    }                                                                            \
  }

#define CONV_STATS_EPILOGUE(STATS)                                               \
  _Pragma("unroll")                                                              \
  for (int ni = 0; ni < 4; ++ni) {                                               \
    lsum[ni] += __shfl_xor(lsum[ni], 16); lsum[ni] += __shfl_xor(lsum[ni], 32);  \
    lsq[ni]  += __shfl_xor(lsq[ni], 16);  lsq[ni]  += __shfl_xor(lsq[ni], 32);   \
  }                                                                              \
  __syncthreads();                                                               \
  red[tid] = 0.f;                                                                \
  __syncthreads();                                                               \
  if (quad == 0) {                                                               \
    _Pragma("unroll")                                                            \
    for (int ni = 0; ni < 4; ++ni) {                                             \
      int co = n_off + ni * 16 + lrow;                                           \
      atomicAdd(&red[co], lsum[ni]);                                             \
      atomicAdd(&red[CH + co], lsq[ni]);                                         \
    }                                                                            \
  }                                                                              \
  __syncthreads();                                                               \
  atomicAdd(&(STATS)[tid], red[tid]);

// ---------------- conv1: q1 -> y i16 + stats ----------------
__global__ __launch_bounds__(256, 2)
void k_conv(const unsigned char* __restrict__ act, const f16* __restrict__ wq,
            short* __restrict__ y, float* __restrict__ stats) {
  __shared__ __align__(16) f16 As[128][72];   // pad 64->72: 2-way bank alias (free, m136)
  __shared__ __align__(16) f16 Bs[128][72];
  __shared__ float red[256];
  CONV_PROLOGUE
  CONV_KLOOP(act, wq, As, Bs)
  float lsum[4] = {0.f, 0.f, 0.f, 0.f}, lsq[4] = {0.f, 0.f, 0.f, 0.f};
#pragma unroll
  for (int mi = 0; mi < 4; ++mi) {
    int prow = p_base + m_off + mi * 16 + quad * 4;
#pragma unroll
    for (int ni = 0; ni < 4; ++ni) {
      int co = n_off + ni * 16 + lrow;
#pragma unroll
      for (int rg = 0; rg < 4; ++rg) {
        float v = acc[mi][ni][rg];            // D: col=lane&15, row=quad*4+rg (m89-verified)
        y[(size_t)(prow + rg) * CH + co] = (short)fminf(fmaxf(v, -32767.f), 32767.f);
        lsum[ni] += v; lsq[ni] += v * v;
      }
    }
  }
  CONV_STATS_EPILOGUE(stats)
}

// ---------------- conv2 pass A: stats only ----------------
__global__ __launch_bounds__(256, 2)
void k_conv_stats(const unsigned char* __restrict__ act, const f16* __restrict__ wq,
                  float* __restrict__ stats) {
  __shared__ __align__(16) f16 As[128][72];
  __shared__ __align__(16) f16 Bs[128][72];
  __shared__ float red[256];
  CONV_PROLOGUE
  CONV_KLOOP(act, wq, As, Bs)
  float lsum[4] = {0.f, 0.f, 0.f, 0.f}, lsq[4] = {0.f, 0.f, 0.f, 0.f};
#pragma unroll
  for (int mi = 0; mi < 4; ++mi)
#pragma unroll
    for (int ni = 0; ni < 4; ++ni)
#pragma unroll
      for (int rg = 0; rg < 4; ++rg) {
        float v = acc[mi][ni][rg];
        lsum[ni] += v; lsq[ni] += v * v;
      }
  CONV_STATS_EPILOGUE(stats)
}

// ---------------- conv2 pass B: fused BN2 + residual -> fp32 NCHW (per-image grid) ----------------
__global__ __launch_bounds__(256, 2)
void k_conv_out(const unsigned char* __restrict__ q2base, const f16* __restrict__ wq,
                const float* __restrict__ bnp, const float* __restrict__ x,
                float* __restrict__ out, int img0) {
  __shared__ __align__(16) char smraw[36864];
  f16 (*As)[72] = (f16(*)[72])smraw;
  f16 (*Bs)[72] = (f16(*)[72])(smraw + 18432);
  f16 (*tile)[132] = (f16(*)[132])smraw;      // [co][pixel], 33,792 B (repurposed)

  const int tid  = threadIdx.x;
  const int wave = tid >> 6, lane = tid & 63;
  const int quad = lane >> 4, lrow = lane & 15;
  const int m_off = (wave >> 1) * 64, n_off = (wave & 1) * 64;
  const int p_base = blockIdx.x * 128;        // 0..3072 local to image (25 blocks)
  const unsigned char* act = q2base + (size_t)blockIdx.y * IMGB;
  const int n_img = img0 + blockIdx.y;

  int a_r[4], a_cc[4], a_h[4], a_w[4], a_ok[4]; long a_base[4];
#pragma unroll
  for (int i = 0; i < 4; ++i) {
    int c = tid + i * 256;
    int r = c >> 3, cc = (c & 7) * 8;
    a_r[i] = r; a_cc[i] = cc;
    int pl = p_base + r;
    a_ok[i] = pl < HWSZ;
    a_h[i] = pl / IMG; a_w[i] = pl - a_h[i] * IMG;
    a_base[i] = (long)pl * CH + cc;
  }
  f32x4 acc[4][4];
#pragma unroll
  for (int mi = 0; mi < 4; ++mi)
#pragma unroll
    for (int ni = 0; ni < 4; ++ni) acc[mi][ni] = (f32x4){0.f, 0.f, 0.f, 0.f};

  for (int kk = 0; kk < 9; ++kk) {
    const int dh = kk / 3 - 1, dw = kk % 3 - 1;
    const int doff = (dh * IMG + dw) * CH;
    for (int ci0 = 0; ci0 < CH; ci0 += 64) {
      __syncthreads();
#pragma unroll
      for (int i = 0; i < 4; ++i) {
        int sh_ = a_h[i] + dh, sw_ = a_w[i] + dw;
        unsigned lo = 0u, hi = 0u;
        if (a_ok[i] && (unsigned)sh_ < (unsigned)IMG && (unsigned)sw_ < (unsigned)IMG) {
          uint2 t = *(const uint2*)(act + a_base[i] + doff + ci0);
          lo = t.x; hi = t.y;
        }
        f16x8 o;
        o[0] = (f16)(float)(lo & 0xFF);  o[1] = (f16)(float)((lo >> 8) & 0xFF);
        o[2] = (f16)(float)((lo >> 16) & 0xFF); o[3] = (f16)(float)(lo >> 24);
        o[4] = (f16)(float)(hi & 0xFF);  o[5] = (f16)(float)((hi >> 8) & 0xFF);
        o[6] = (f16)(float)((hi >> 16) & 0xFF); o[7] = (f16)(float)(hi >> 24);
        *(f16x8*)&As[a_r[i]][a_cc[i]] = o;
      }
#pragma unroll
      for (int i = 0; i < 4; ++i)
        *(uint4*)&Bs[a_r[i]][a_cc[i]] =
            *(const uint4*)(wq + (size_t)kk * (CH * CH) + a_r[i] * CH + ci0 + a_cc[i]);
      __syncthreads();
#pragma unroll
      for (int ks = 0; ks < 2; ++ks) {
        const int kof = ks * 32 + quad * 8;
        f16x8 af[4], bfr[4];
#pragma unroll
        for (int mi = 0; mi < 4; ++mi) af[mi]  = *(const f16x8*)&As[m_off + mi * 16 + lrow][kof];
#pragma unroll
        for (int ni = 0; ni < 4; ++ni) bfr[ni] = *(const f16x8*)&Bs[n_off + ni * 16 + lrow][kof];
#pragma unroll
        for (int mi = 0; mi < 4; ++mi)
#pragma unroll
          for (int ni = 0; ni < 4; ++ni)
            acc[mi][ni] = __builtin_amdgcn_mfma_f32_16x16x32_f16(af[mi], bfr[ni], acc[mi][ni], 0, 0, 0);
      }
    }
  }

  // BN2 into f16 LDS tile [co][pixel] (values |v|<=~8; f16 rounding ~0.004 << 0.153 budget)
  __syncthreads();
#pragma unroll
  for (int ni = 0; ni < 4; ++ni) {
    int co = n_off + ni * 16 + lrow;
    float sc = bnp[co], sh = bnp[CH + co];
#pragma unroll
    for (int mi = 0; mi < 4; ++mi) {
      int pr = m_off + mi * 16 + quad * 4;
      f16x8 dummy;
      f16 q0 = (f16)(acc[mi][ni][0] * sc + sh);
      f16 q1 = (f16)(acc[mi][ni][1] * sc + sh);
      f16 q2 = (f16)(acc[mi][ni][2] * sc + sh);
      f16 q3 = (f16)(acc[mi][ni][3] * sc + sh);
      (void)dummy;
      tile[co][pr]     = q0;
      tile[co][pr + 1] = q1;
      tile[co][pr + 2] = q2;
      tile[co][pr + 3] = q3;
    }
  }
  __syncthreads();

  // residual add + NCHW fp32 store: thread -> (channel, 64-pixel segment)
  int c = tid >> 1, seg = tid & 1;
  int pl0 = p_base + seg * 64;
  if (pl0 < HWSZ) {
    size_t gb = ((size_t)n_img * CH + c) * HWSZ + pl0;
    const float* xp = x + gb;
    float* op = out + gb;
    const f16* tr = &tile[c][seg * 64];
#pragma unroll
    for (int j = 0; j < 64; j += 4) {
      f32x4 xv = *(const f32x4*)(xp + j);
      f32x4 ov;
      ov[0] = (float)tr[j]     + xv[0];
      ov[1] = (float)tr[j + 1] + xv[1];
      ov[2] = (float)tr[j + 2] + xv[2];
      ov[3] = (float)tr[j + 3] + xv[3];
      *(f32x4*)(op + j) = ov;
    }
  }
}

// ---------------- BN finalize (acc units: y_real = acc * alpha/105) ----------------
__global__ void k_bnfin(const float* __restrict__ stats,
                        const unsigned* __restrict__ abits,
                        const float* __restrict__ gamma,
                        const float* __restrict__ beta,
                        float* __restrict__ bnpar) {
  int c = threadIdx.x;
  const float inv = 1.f / (float)NPIX;
  float gs   = (__uint_as_float(abits[0]) + 1e-12f) * (1.f / 105.f);
  float mean = stats[c] * inv;
  float var  = fmaxf(stats[CH + c] * inv - mean * mean, 0.f);   // clamp: never NaN
  float sc   = gamma[c] * gs * rsqrtf(gs * gs * var + BNEPS);
  bnpar[c]      = sc;
  bnpar[CH + c] = beta[c] - sc * mean;
}

// ---------------- BN1 apply + act quant: y i16 -> q2 u8 ----------------
__global__ void k_bnq(const short* __restrict__ y, const float* __restrict__ bnp,
                      unsigned char* __restrict__ q) {
  size_t i = (size_t)blockIdx.x * 256 + threadIdx.x;   // 8 elems/thread
  short8 v = ((const short8*)y)[i];
  int c0 = (int)((i * 8) & (CH - 1));
  unsigned lo = 0, hi = 0;
#pragma unroll
  for (int j = 0; j < 4; ++j) {
    float t = (float)v[j] * bnp[c0 + j] + bnp[CH + c0 + j];
    t = fminf(fmaxf(t, 0.f), 1.f);
    lo |= ((unsigned)(int)rintf(t * 15.f)) << (8 * j);
  }
#pragma unroll
  for (int j = 4; j < 8; ++j) {
    float t = (float)v[j] * bnp[c0 + j] + bnp[CH + c0 + j];
    t = fminf(fmaxf(t, 0.f), 1.f);
    hi |= ((unsigned)(int)rintf(t * 15.f)) << (8 * (j - 4));
  }
  ((uint2*)q)[i] = (uint2){lo, hi};
}

extern "C" void kernel_launch(void* const* d_in, const int* in_sizes, int n_in,
                              void* d_out, int out_size, void* d_ws, size_t ws_size,
                              hipStream_t stream) {
  (void)in_sizes; (void)n_in; (void)out_size; (void)ws_size;
  const float* x  = (const float*)d_in[0];
  const float* w1 = (const float*)d_in[1];
  const float* w2 = (const float*)d_in[2];
  const float* g1 = (const float*)d_in[3];
  const float* b1 = (const float*)d_in[4];
  const float* g2 = (const float*)d_in[5];
  const float* b2 = (const float*)d_in[6];
  float* out = (float*)d_out;

  char* dob = (char*)d_out;
  unsigned char* q1  = (unsigned char*)dob;              // [0, 25.69M)
  short*         ybuf = (short*)(dob + YOFF);            // [25.69M, 77.07M)
  unsigned char* q2  = (unsigned char*)(dob + Q2OFF);    // [77.07M, 102.76M)
  f16*           wq1 = (f16*)(dob + Q2OFF);              // parked in q2 region (dead before q2)

  char* ws = (char*)d_ws;
  unsigned* alpha_bits = (unsigned*)ws;
  float* stats1 = (float*)(ws + 256);
  float* stats2 = (float*)(ws + 1280);
  float* bnp1   = (float*)(ws + 2304);
  float* bnp2   = (float*)(ws + 3328);
  f16*   wq2    = (f16*)(ws + 4608);                     // 294,912 B
  unsigned char* q63 = (unsigned char*)(ws + 299520);    // 401,408 B -> ws use 700,928 B

  hipMemsetAsync(ws, 0, 4608, stream);                   // alpha + stats + bnpar

  k_wmax  <<<64, 256, 0, stream>>>(w1, w2, alpha_bits);
  k_wquant<<<2 * WELEMS / 256, 256, 0, stream>>>(w1, w2, alpha_bits, wq1, wq2);
  k_actq  <<<dim3(98, 4, 64), dim3(32, 8), 0, stream>>>(x, q1);

  // conv1 -> y + stats1 ; BN1 ; y -> q2
  k_conv      <<<NPIX / 128, 256, 0, stream>>>(q1, wq1, ybuf, stats1);
  k_bnfin     <<<1, 128, 0, stream>>>(stats1, alpha_bits + 0, g1, b1, bnp1);
  k_bnq       <<<NPIX * CH / 2048, 256, 0, stream>>>(ybuf, bnp1, q2);

  // conv2 stats ; BN2 params
  k_conv_stats<<<NPIX / 128, 256, 0, stream>>>(q2, wq2, stats2);
  k_bnfin     <<<1, 128, 0, stream>>>(stats2, alpha_bits + 1, g2, b2, bnp2);

  // save q2 image 63 (its storage is overwritten while still needed)
  hipMemcpyAsync(q63, q2 + (size_t)63 * IMGB, IMGB, hipMemcpyDeviceToDevice, stream);

  // fused conv2 + BN2 + residual -> out (fp32 NCHW).  out[n] destroys q2[4(n-48)..+3] (n>=48):
  // batches ordered so writes only destroy already-consumed q2 images.
  k_conv_out<<<dim3(25, 48), 256, 0, stream>>>(q2,                     wq2, bnp2, x, out, 0);   // n 0..47
  k_conv_out<<<dim3(25, 12), 256, 0, stream>>>(q2 + (size_t)48 * IMGB, wq2, bnp2, x, out, 48);  // n 48..59
  k_conv_out<<<dim3(25,  3), 256, 0, stream>>>(q2 + (size_t)60 * IMGB, wq2, bnp2, x, out, 60);  // n 60..62
  k_conv_out<<<dim3(25,  1), 256, 0, stream>>>(q63,                    wq2, bnp2, x, out, 63);  // n 63 (ws copy)
}

// Round 7
// 509.517 us; speedup vs baseline: 1.3645x; 1.3645x over previous
//
#include <hip/hip_runtime.h>

#define CH    128
#define IMG   56
#define PADW  58
#define HWSZ  3136
#define NPIX  200704        // 64*3136
#define WELEMS 147456       // 128*128*9
#define BNEPS 1e-5f
#define PADB  430592        // 58*58*128 bytes, one halo-padded fp8 image

// ---- d_out layout (102,760,448 B, fp32 output) ----
//  q1p fp8 padded NHWC : [0, 27,557,888)
//  y   i16 NHWC        : [27,557,888, 78,938,112)
//  wq1 fp8 [kk][co][ci]: [78,938,112, 79,085,568)
//  q2p fp8 padded NHWC : [0, 27,557,888)  (overwrites dead q1p)
#define YOFF   27557888u
#define WQ1OFF 78938112u
// ---- d_ws layout (582,656 B used; 700,928 proven available in round 6) ----
//  alpha@0, stats1@256, stats2@1280, bnp1@2304, bnp2@3328  (4,608)
//  wq2 fp8: [4,608, 152,064)
//  q2p image-0 copy: [152,064, 582,656)

typedef float f32x4 __attribute__((ext_vector_type(4)));
typedef short short8 __attribute__((ext_vector_type(8)));
typedef _Float16 f16;

__device__ __forceinline__ void async16(const void* g, void* l) {
  __builtin_amdgcn_global_load_lds(
      (const __attribute__((address_space(1))) unsigned int*)g,
      (__attribute__((address_space(3))) unsigned int*)l, 16, 0, 0);
}
__device__ __forceinline__ unsigned char fp8enc(float v) {   // exact for small ints
  return (unsigned char)(__builtin_amdgcn_cvt_pk_fp8_f32(v, v, 0, false) & 0xFF);
}

// ---------------- weight absmax ----------------
__global__ void k_wmax(const float* __restrict__ w1, const float* __restrict__ w2,
                       unsigned* __restrict__ alpha_bits) {
  int idx = blockIdx.x * 256 + threadIdx.x;
  float m1 = 0.f, m2 = 0.f;
  for (int i = idx; i < WELEMS; i += gridDim.x * 256) {
    m1 = fmaxf(m1, fabsf(w1[i]));
    m2 = fmaxf(m2, fabsf(w2[i]));
  }
#pragma unroll
  for (int off = 32; off > 0; off >>= 1) {
    m1 = fmaxf(m1, __shfl_xor(m1, off));
    m2 = fmaxf(m2, __shfl_xor(m2, off));
  }
  __shared__ float s1[4], s2[4];
  int wave = threadIdx.x >> 6;
  if ((threadIdx.x & 63) == 0) { s1[wave] = m1; s2[wave] = m2; }
  __syncthreads();
  if (threadIdx.x == 0) {
    m1 = fmaxf(fmaxf(s1[0], s1[1]), fmaxf(s1[2], s1[3]));
    m2 = fmaxf(fmaxf(s2[0], s2[1]), fmaxf(s2[2], s2[3]));
    atomicMax(&alpha_bits[0], __float_as_uint(m1));
    atomicMax(&alpha_bits[1], __float_as_uint(m2));
  }
}

// ---------------- weight quantize to integer fp8 (-7..7), OIHW -> [kk][co][ci] ----------------
__global__ void k_wquant(const float* __restrict__ w1, const float* __restrict__ w2,
                         const unsigned* __restrict__ alpha_bits,
                         unsigned char* __restrict__ wq1, unsigned char* __restrict__ wq2) {
  int idx = blockIdx.x * 256 + threadIdx.x;
  int t = idx >= WELEMS;
  int j = t ? idx - WELEMS : idx;
  int kk  = j >> 14;
  int rem = j & 16383;
  int co = rem >> 7, ci = rem & 127;
  float alpha = __uint_as_float(alpha_bits[t]) + 1e-12f;
  float v  = (t ? w2 : w1)[co * 1152 + ci * 9 + kk];
  float wc = fminf(fmaxf(v / alpha, -1.f), 1.f);
  (t ? wq2 : wq1)[j] = fp8enc(rintf(wc * 7.f));
}

// ---------------- act quant to fp8 (0..15) + NCHW fp32 -> padded NHWC ----------------
__global__ void k_actq(const float* __restrict__ x, unsigned char* __restrict__ qx) {
  __shared__ float tile[32][33];
  int n = blockIdx.z, p0 = blockIdx.x * 32, c0 = blockIdx.y * 32;
  int tx = threadIdx.x, ty = threadIdx.y;
  const float* xs = x + ((size_t)n * CH + c0) * HWSZ;
#pragma unroll
  for (int r = 0; r < 4; ++r) {
    int c = ty + r * 8;
    float v = xs[(size_t)c * HWSZ + p0 + tx];       // coalesced along p
    v = fminf(fmaxf(v, 0.f), 1.f);                  // kills NaN too
    tile[c][tx] = rintf(v * 15.f);
  }
  __syncthreads();
  unsigned char* qb = qx + (size_t)n * PADB;
#pragma unroll
  for (int r = 0; r < 4; ++r) {
    int pl = p0 + ty + r * 8;
    int h = pl / IMG, w = pl - h * IMG;
    qb[((h + 1) * PADW + (w + 1)) * 128 + c0 + tx] = fp8enc(tile[tx][ty + r * 8]);
  }
}

// ============ conv core: fp8 acts (halo-padded) x fp8 weights, global_load_lds + swizzle ======
#define CONV_SETUP(PCALC)                                                        \
  const int tid  = threadIdx.x;                                                  \
  const int lane = tid & 63;                                                     \
  const int quad = lane >> 4, lrow = lane & 15;                                  \
  const int m_off = ((tid >> 6) >> 1) * 64, n_off = ((tid >> 6) & 1) * 64;       \
  char* As = smem; char* Bs = smem + 16384;                                      \
  const unsigned char* asrc[4]; int boff[4], ldsoff[4];                          \
  _Pragma("unroll")                                                              \
  for (int i = 0; i < 4; ++i) {                                                  \
    int c = i * 256 + tid;                                                       \
    int r = c >> 3;                                                              \
    int srccol = ((c & 7) ^ (r & 7)) * 16;   /* XOR-swizzled 16B chunks */       \
    ldsoff[i] = (i * 256 + (tid & ~63)) * 16;                                    \
    PCALC                                                                        \
    boff[i] = r * 128 + srccol;                                                  \
  }                                                                              \
  int axcol[4];                                                                  \
  _Pragma("unroll")                                                              \
  for (int ks = 0; ks < 4; ++ks)                                                 \
    axcol[ks] = ((((ks << 1) | (quad >> 1)) ^ (lrow & 7)) << 4) | ((quad & 1) << 3); \
  f32x4 acc[4][4];                                                               \
  _Pragma("unroll")                                                              \
  for (int mi = 0; mi < 4; ++mi)                                                 \
    _Pragma("unroll")                                                            \
    for (int ni = 0; ni < 4; ++ni) acc[mi][ni] = (f32x4){0.f, 0.f, 0.f, 0.f};

#define PCALC_GLOBAL                                                             \
    int p = blockIdx.x * 128 + r;                                                \
    int n = p / HWSZ, l = p - n * HWSZ;                                          \
    int h = l / IMG, w = l - h * IMG;                                            \
    asrc[i] = act + (size_t)n * PADB + ((h + 1) * PADW + (w + 1)) * 128 + srccol;

#define PCALC_IMG                                                                \
    int p = blockIdx.x * 128 + r;                                                \
    if (p > HWSZ - 1) p = HWSZ - 1;          /* clamp tail; masked at store */    \
    int h = p / IMG, w = p - h * IMG;                                            \
    asrc[i] = act + ((h + 1) * PADW + (w + 1)) * 128 + srccol;

#define CONV_KLOOP(WQ)                                                           \
  for (int kk = 0; kk < 9; ++kk) {                                               \
    const int doff = ((kk / 3 - 1) * PADW + (kk % 3 - 1)) * 128;                 \
    __syncthreads();                                                             \
    _Pragma("unroll")                                                            \
    for (int i = 0; i < 4; ++i) async16(asrc[i] + doff, As + ldsoff[i]);         \
    _Pragma("unroll")                                                            \
    for (int i = 0; i < 4; ++i) async16((WQ) + kk * 16384 + boff[i], Bs + ldsoff[i]); \
    __syncthreads();                                                             \
    _Pragma("unroll")                                                            \
    for (int ks = 0; ks < 4; ++ks) {                                             \
      long af[4], bf[4];                                                         \
      _Pragma("unroll")                                                          \
      for (int mi = 0; mi < 4; ++mi)                                             \
        af[mi] = *(const long*)(As + (m_off + mi * 16 + lrow) * 128 + axcol[ks]); \
      _Pragma("unroll")                                                          \
      for (int ni = 0; ni < 4; ++ni)                                             \
        bf[ni] = *(const long*)(Bs + (n_off + ni * 16 + lrow) * 128 + axcol[ks]); \
      _Pragma("unroll")                                                          \
      for (int mi = 0; mi < 4; ++mi)                                             \
        _Pragma("unroll")                                                        \
        for (int ni = 0; ni < 4; ++ni)                                           \
          acc[mi][ni] = __builtin_amdgcn_mfma_f32_16x16x32_fp8_fp8(af[mi], bf[ni], acc[mi][ni], 0, 0, 0); \
    }                                                                            \
  }

#define CONV_STATS_EPILOGUE(STATS)                                               \
  _Pragma("unroll")                                                              \
  for (int ni = 0; ni < 4; ++ni) {                                               \
    lsum[ni] += __shfl_xor(lsum[ni], 16); lsum[ni] += __shfl_xor(lsum[ni], 32);  \
    lsq[ni]  += __shfl_xor(lsq[ni], 16);  lsq[ni]  += __shfl_xor(lsq[ni], 32);   \
  }                                                                              \
  __syncthreads();                                                               \
  float* red = (float*)(smem + 32768);                                           \
  red[tid] = 0.f;                                                                \
  __syncthreads();                                                               \
  if (quad == 0) {                                                               \
    _Pragma("unroll")                                                            \
    for (int ni = 0; ni < 4; ++ni) {                                             \
      int co = n_off + ni * 16 + lrow;                                           \
      atomicAdd(&red[co], lsum[ni]);                                             \
      atomicAdd(&red[CH + co], lsq[ni]);                                         \
    }                                                                            \
  }                                                                              \
  __syncthreads();                                                               \
  atomicAdd(&(STATS)[tid], red[tid]);

// ---------------- conv1: q1p -> y i16 + stats1 ----------------
__global__ __launch_bounds__(256, 3)
void k_conv(const unsigned char* __restrict__ act, const unsigned char* __restrict__ wq,
            short* __restrict__ y, float* __restrict__ stats) {
  __shared__ __align__(16) char smem[33792];
  CONV_SETUP(PCALC_GLOBAL)
  CONV_KLOOP(wq)
  float lsum[4] = {0.f, 0.f, 0.f, 0.f}, lsq[4] = {0.f, 0.f, 0.f, 0.f};
#pragma unroll
  for (int mi = 0; mi < 4; ++mi) {
    int prow = blockIdx.x * 128 + m_off + mi * 16 + quad * 4;
#pragma unroll
    for (int ni = 0; ni < 4; ++ni) {
      int co = n_off + ni * 16 + lrow;
#pragma unroll
      for (int rg = 0; rg < 4; ++rg) {
        float v = acc[mi][ni][rg];        // D: col=lane&15, row=quad*4+rg (verified round 6)
        y[(size_t)(prow + rg) * CH + co] = (short)fminf(fmaxf(v, -32767.f), 32767.f);
        lsum[ni] += v; lsq[ni] += v * v;
      }
    }
  }
  CONV_STATS_EPILOGUE(stats)
}

// ---------------- conv2 pass A: stats only ----------------
__global__ __launch_bounds__(256, 3)
void k_conv_stats(const unsigned char* __restrict__ act, const unsigned char* __restrict__ wq,
                  float* __restrict__ stats) {
  __shared__ __align__(16) char smem[33792];
  CONV_SETUP(PCALC_GLOBAL)
  CONV_KLOOP(wq)
  float lsum[4] = {0.f, 0.f, 0.f, 0.f}, lsq[4] = {0.f, 0.f, 0.f, 0.f};
#pragma unroll
  for (int mi = 0; mi < 4; ++mi)
#pragma unroll
    for (int ni = 0; ni < 4; ++ni)
#pragma unroll
      for (int rg = 0; rg < 4; ++rg) {
        float v = acc[mi][ni][rg];
        lsum[ni] += v; lsq[ni] += v * v;
      }
  CONV_STATS_EPILOGUE(stats)
}

// ---------------- conv2 pass B: fused BN2 + residual -> fp32 NCHW (per-image) ----------------
__global__ __launch_bounds__(256, 3)
void k_conv_out(const unsigned char* __restrict__ actbase, const unsigned char* __restrict__ wq,
                const float* __restrict__ bnp, const float* __restrict__ x,
                float* __restrict__ out, int img0) {
  __shared__ __align__(16) char smem[33792];
  const unsigned char* act = actbase + (size_t)blockIdx.y * PADB;
  CONV_SETUP(PCALC_IMG)
  CONV_KLOOP(wq)

  // BN2 into f16 tile [co][pixel] (|v|<=~8, f16 rounding ~0.004 << budget)
  __syncthreads();
  f16 (*tile)[132] = (f16(*)[132])smem;     // 128*132*2 = 33,792 B
#pragma unroll
  for (int ni = 0; ni < 4; ++ni) {
    int co = n_off + ni * 16 + lrow;
    float sc = bnp[co], sh = bnp[CH + co];
#pragma unroll
    for (int mi = 0; mi < 4; ++mi) {
      int pr = m_off + mi * 16 + quad * 4;
#pragma unroll
      for (int rg = 0; rg < 4; ++rg)
        tile[co][pr + rg] = (f16)(acc[mi][ni][rg] * sc + sh);
    }
  }
  __syncthreads();

  // residual add + NCHW fp32 store
  int c = tid >> 1, seg = tid & 1;
  int pl0 = blockIdx.x * 128 + seg * 64;
  if (pl0 < HWSZ) {
    size_t gb = ((size_t)(img0 + blockIdx.y) * CH + c) * HWSZ + pl0;
    const float* xp = x + gb;
    float* op = out + gb;
    const f16* tr = &tile[c][seg * 64];
#pragma unroll
    for (int j = 0; j < 64; j += 4) {
      f32x4 xv = *(const f32x4*)(xp + j);
      f32x4 ov;
      ov[0] = (float)tr[j]     + xv[0];
      ov[1] = (float)tr[j + 1] + xv[1];
      ov[2] = (float)tr[j + 2] + xv[2];
      ov[3] = (float)tr[j + 3] + xv[3];
      *(f32x4*)(op + j) = ov;
    }
  }
}

// ---------------- BN finalize (acc units: y_real = acc * alpha/105) ----------------
__global__ void k_bnfin(const float* __restrict__ stats, const unsigned* __restrict__ abits,
                        const float* __restrict__ gamma, const float* __restrict__ beta,
                        float* __restrict__ bnpar) {
  int c = threadIdx.x;
  const float inv = 1.f / (float)NPIX;
  float gs   = (__uint_as_float(abits[0]) + 1e-12f) * (1.f / 105.f);
  float mean = stats[c] * inv;
  float var  = fmaxf(stats[CH + c] * inv - mean * mean, 0.f);
  float sc   = gamma[c] * gs * rsqrtf(gs * gs * var + BNEPS);
  bnpar[c]      = sc;
  bnpar[CH + c] = beta[c] - sc * mean;
}

// ---------------- BN1 apply + act quant: y i16 -> q2p fp8 (padded NHWC) ----------------
__global__ void k_bnq(const short* __restrict__ y, const float* __restrict__ bnp,
                      unsigned char* __restrict__ q) {
  size_t i = (size_t)blockIdx.x * 256 + threadIdx.x;   // 8 elems/thread
  short8 v = ((const short8*)y)[i];
  int c0 = (int)((i * 8) & (CH - 1));
  int pix = (int)(i >> 4);
  int n = pix / HWSZ, l = pix - n * HWSZ;
  int h = l / IMG, w = l - h * IMG;
  float t[8];
#pragma unroll
  for (int j = 0; j < 8; ++j) {
    float u = (float)v[j] * bnp[c0 + j] + bnp[CH + c0 + j];
    t[j] = rintf(fminf(fmaxf(u, 0.f), 1.f) * 15.f);
  }
  int lo = __builtin_amdgcn_cvt_pk_fp8_f32(t[0], t[1], 0, false);
  lo     = __builtin_amdgcn_cvt_pk_fp8_f32(t[2], t[3], lo, true);
  int hi = __builtin_amdgcn_cvt_pk_fp8_f32(t[4], t[5], 0, false);
  hi     = __builtin_amdgcn_cvt_pk_fp8_f32(t[6], t[7], hi, true);
  *(uint2*)(q + (size_t)n * PADB + ((h + 1) * PADW + (w + 1)) * 128 + c0) =
      (uint2){(unsigned)lo, (unsigned)hi};
}

extern "C" void kernel_launch(void* const* d_in, const int* in_sizes, int n_in,
                              void* d_out, int out_size, void* d_ws, size_t ws_size,
                              hipStream_t stream) {
  (void)in_sizes; (void)n_in; (void)out_size; (void)ws_size;
  const float* x  = (const float*)d_in[0];
  const float* w1 = (const float*)d_in[1];
  const float* w2 = (const float*)d_in[2];
  const float* g1 = (const float*)d_in[3];
  const float* b1 = (const float*)d_in[4];
  const float* g2 = (const float*)d_in[5];
  const float* b2 = (const float*)d_in[6];
  float* out = (float*)d_out;

  char* dob = (char*)d_out;
  unsigned char* q1p = (unsigned char*)dob;              // padded fp8, [0, 27.56M)
  unsigned char* q2p = (unsigned char*)dob;              // same region (q1p dead by then)
  short*         ybuf = (short*)(dob + YOFF);            // i16 NHWC
  unsigned char* wq1 = (unsigned char*)(dob + WQ1OFF);   // dead before out[49..] written

  char* ws = (char*)d_ws;
  unsigned* alpha_bits = (unsigned*)ws;
  float* stats1 = (float*)(ws + 256);
  float* stats2 = (float*)(ws + 1280);
  float* bnp1   = (float*)(ws + 2304);
  float* bnp2   = (float*)(ws + 3328);
  unsigned char* wq2  = (unsigned char*)(ws + 4608);     // 147,456 B
  unsigned char* q2p0 = (unsigned char*)(ws + 152064);   // 430,592 B (image-0 copy)

  hipMemsetAsync(ws, 0, 4608, stream);
  k_wmax  <<<64, 256, 0, stream>>>(w1, w2, alpha_bits);
  k_wquant<<<2 * WELEMS / 256, 256, 0, stream>>>(w1, w2, alpha_bits, wq1, wq2);

  hipMemsetAsync(q1p, 0, (size_t)64 * PADB, stream);     // halo zeros
  k_actq  <<<dim3(98, 4, 64), dim3(32, 8), 0, stream>>>(x, q1p);

  k_conv  <<<NPIX / 128, 256, 0, stream>>>(q1p, wq1, ybuf, stats1);
  k_bnfin <<<1, 128, 0, stream>>>(stats1, alpha_bits + 0, g1, b1, bnp1);

  hipMemsetAsync(q2p, 0, (size_t)64 * PADB, stream);     // q1p dead; re-zero halos
  k_bnq   <<<NPIX * CH / 2048, 256, 0, stream>>>(ybuf, bnp1, q2p);

  k_conv_stats<<<NPIX / 128, 256, 0, stream>>>(q2p, wq2, stats2);
  k_bnfin <<<1, 128, 0, stream>>>(stats2, alpha_bits + 1, g2, b2, bnp2);

  hipMemcpyAsync(q2p0, q2p, PADB, hipMemcpyDeviceToDevice, stream);  // save image 0

  // fused conv2+BN2+residual -> out, DESCENDING batches.
  // out[n] overlaps q2p[m] only for m in (3.729n-1, 3.729(n+1)) -> m > n for n>=1.
  k_conv_out<<<dim3(25, 46), 256, 0, stream>>>(q2p + (size_t)18 * PADB, wq2, bnp2, x, out, 18); // 18..63
  k_conv_out<<<dim3(25,  9), 256, 0, stream>>>(q2p + (size_t)9  * PADB, wq2, bnp2, x, out,  9); // 9..17
  k_conv_out<<<dim3(25,  5), 256, 0, stream>>>(q2p + (size_t)4  * PADB, wq2, bnp2, x, out,  4); // 4..8
  k_conv_out<<<dim3(25,  2), 256, 0, stream>>>(q2p + (size_t)2  * PADB, wq2, bnp2, x, out,  2); // 2..3
  k_conv_out<<<dim3(25,  1), 256, 0, stream>>>(q2p + (size_t)1  * PADB, wq2, bnp2, x, out,  1); // 1
  k_conv_out<<<dim3(25,  1), 256, 0, stream>>>(q2p0,                    wq2, bnp2, x, out,  0); // 0 (ws copy)
}

// Round 8
// 377.853 us; speedup vs baseline: 1.8399x; 1.3485x over previous
//
#include <hip/hip_runtime.h>

#define CH    128
#define IMG   56
#define PADW  58
#define HWSZ  3136
#define NPIX  200704        // 64*3136
#define WELEMS 147456       // 128*128*9
#define BNEPS 1e-5f
#define PADB  430592        // 58*58*128, one halo-padded fp8 image
#define YOFF  27557888u     // y1 i16 NHWC in d_out
#define Y2OFF_B 51380224u   // Plan B: y2 in d_out top half
#define WQ1OFF_B 78938112u  // Plan B: wq1 parked above y1

typedef float f32x4 __attribute__((ext_vector_type(4)));
typedef short short8 __attribute__((ext_vector_type(8)));
typedef _Float16 f16;

__device__ __forceinline__ void async16(const void* g, void* l) {
  __builtin_amdgcn_global_load_lds(
      (const __attribute__((address_space(1))) unsigned int*)g,
      (__attribute__((address_space(3))) unsigned int*)l, 16, 0, 0);
}
__device__ __forceinline__ unsigned char fp8enc(float v) {   // exact for small ints
  return (unsigned char)(__builtin_amdgcn_cvt_pk_fp8_f32(v, v, 0, false) & 0xFF);
}
// inline BN-param compute (per-block, channels 0..127 -> bnpS[0..255])
__device__ __forceinline__ void bn_inline(int lin, const float* stats, const unsigned* abits,
                                          const float* g, const float* b, float* bnpS) {
  if (lin < 128) {
    const float inv = 1.f / (float)NPIX;
    float gs   = (__uint_as_float(*abits) + 1e-12f) * (1.f / 105.f);
    float mean = stats[lin] * inv;
    float var  = fmaxf(stats[CH + lin] * inv - mean * mean, 0.f);
    float sc   = g[lin] * gs * rsqrtf(gs * gs * var + BNEPS);
    bnpS[lin]      = sc;
    bnpS[CH + lin] = b[lin] - sc * mean;
  }
}
// zero the 29,184-byte halo of one padded image (1824 16B chunks, 256 threads)
__device__ __forceinline__ void halo_zero(unsigned char* qb, int lin) {
  for (int i = lin; i < 1824; i += 256) {
    size_t off;
    if (i < 464)      off = (size_t)i * 16;                                  // row 0
    else if (i < 928) off = (size_t)57 * PADW * 128 + (size_t)(i - 464) * 16; // row 57
    else {
      int j = i - 928, loc = j >> 3, sub = j & 7;
      int row = 1 + (loc >> 1), col = (loc & 1) ? 57 : 0;
      off = ((size_t)row * PADW + col) * 128 + (size_t)sub * 16;
    }
    *(uint4*)(qb + off) = (uint4){0u, 0u, 0u, 0u};
  }
}

// ---------------- weight absmax ----------------
__global__ void k_wmax(const float* __restrict__ w1, const float* __restrict__ w2,
                       unsigned* __restrict__ alpha_bits) {
  int idx = blockIdx.x * 256 + threadIdx.x;
  float m1 = 0.f, m2 = 0.f;
  for (int i = idx; i < WELEMS; i += gridDim.x * 256) {
    m1 = fmaxf(m1, fabsf(w1[i]));
    m2 = fmaxf(m2, fabsf(w2[i]));
  }
#pragma unroll
  for (int off = 32; off > 0; off >>= 1) {
    m1 = fmaxf(m1, __shfl_xor(m1, off));
    m2 = fmaxf(m2, __shfl_xor(m2, off));
  }
  __shared__ float s1[4], s2[4];
  int wave = threadIdx.x >> 6;
  if ((threadIdx.x & 63) == 0) { s1[wave] = m1; s2[wave] = m2; }
  __syncthreads();
  if (threadIdx.x == 0) {
    m1 = fmaxf(fmaxf(s1[0], s1[1]), fmaxf(s1[2], s1[3]));
    m2 = fmaxf(fmaxf(s2[0], s2[1]), fmaxf(s2[2], s2[3]));
    atomicMax(&alpha_bits[0], __float_as_uint(m1));
    atomicMax(&alpha_bits[1], __float_as_uint(m2));
  }
}

// ---------------- weight quantize to integer fp8 (-7..7), OIHW -> [kk][co][ci] ----------------
__global__ void k_wquant(const float* __restrict__ w1, const float* __restrict__ w2,
                         const unsigned* __restrict__ alpha_bits,
                         unsigned char* __restrict__ wq1, unsigned char* __restrict__ wq2) {
  int idx = blockIdx.x * 256 + threadIdx.x;
  int t = idx >= WELEMS;
  int j = t ? idx - WELEMS : idx;
  int kk  = j >> 14;
  int rem = j & 16383;
  int co = rem >> 7, ci = rem & 127;
  float alpha = __uint_as_float(alpha_bits[t]) + 1e-12f;
  float v  = (t ? w2 : w1)[co * 1152 + ci * 9 + kk];
  float wc = fminf(fmaxf(v / alpha, -1.f), 1.f);
  (t ? wq2 : wq1)[j] = fp8enc(rintf(wc * 7.f));
}

// ---------------- act quant to fp8 (0..15) + NCHW fp32 -> padded NHWC (+halo zero) ----------------
__global__ void k_actq(const float* __restrict__ x, unsigned char* __restrict__ qx) {
  __shared__ float tile[32][33];
  int n = blockIdx.z, p0 = blockIdx.x * 32, c0 = blockIdx.y * 32;
  int tx = threadIdx.x, ty = threadIdx.y, lin = ty * 32 + tx;
  unsigned char* qb = qx + (size_t)n * PADB;
  if (blockIdx.x == 0 && blockIdx.y == 0) halo_zero(qb, lin);
  const float* xs = x + ((size_t)n * CH + c0) * HWSZ;
#pragma unroll
  for (int r = 0; r < 4; ++r) {
    int c = ty + r * 8;
    float v = xs[(size_t)c * HWSZ + p0 + tx];       // coalesced along p
    v = fminf(fmaxf(v, 0.f), 1.f);                  // kills NaN too
    tile[c][tx] = rintf(v * 15.f);
  }
  __syncthreads();
#pragma unroll
  for (int r = 0; r < 4; ++r) {
    int pl = p0 + ty + r * 8;
    int h = pl / IMG, w = pl - h * IMG;
    qb[((h + 1) * PADW + (w + 1)) * 128 + c0 + tx] = fp8enc(tile[tx][ty + r * 8]);
  }
}

// ============ conv core (round-7 proven): fp8 acts (halo-padded) x fp8 weights ============
#define CONV_SETUP(PCALC)                                                        \
  const int tid  = threadIdx.x;                                                  \
  const int lane = tid & 63;                                                     \
  const int quad = lane >> 4, lrow = lane & 15;                                  \
  const int m_off = ((tid >> 6) >> 1) * 64, n_off = ((tid >> 6) & 1) * 64;       \
  char* As = smem; char* Bs = smem + 16384;                                      \
  const unsigned char* asrc[4]; int boff[4], ldsoff[4];                          \
  _Pragma("unroll")                                                              \
  for (int i = 0; i < 4; ++i) {                                                  \
    int c = i * 256 + tid;                                                       \
    int r = c >> 3;                                                              \
    int srccol = ((c & 7) ^ (r & 7)) * 16;   /* XOR-swizzled 16B chunks */       \
    ldsoff[i] = (i * 256 + (tid & ~63)) * 16;                                    \
    PCALC                                                                        \
    boff[i] = r * 128 + srccol;                                                  \
  }                                                                              \
  int axcol[4];                                                                  \
  _Pragma("unroll")                                                              \
  for (int ks = 0; ks < 4; ++ks)                                                 \
    axcol[ks] = ((((ks << 1) | (quad >> 1)) ^ (lrow & 7)) << 4) | ((quad & 1) << 3); \
  f32x4 acc[4][4];                                                               \
  _Pragma("unroll")                                                              \
  for (int mi = 0; mi < 4; ++mi)                                                 \
    _Pragma("unroll")                                                            \
    for (int ni = 0; ni < 4; ++ni) acc[mi][ni] = (f32x4){0.f, 0.f, 0.f, 0.f};

#define PCALC_GLOBAL                                                             \
    int p = blockIdx.x * 128 + r;                                                \
    int n = p / HWSZ, l = p - n * HWSZ;                                          \
    int h = l / IMG, w = l - h * IMG;                                            \
    asrc[i] = act + (size_t)n * PADB + ((h + 1) * PADW + (w + 1)) * 128 + srccol;

#define PCALC_IMG                                                                \
    int p = blockIdx.x * 128 + r;                                                \
    if (p > HWSZ - 1) p = HWSZ - 1;          /* clamp tail; masked at store */    \
    int h = p / IMG, w = p - h * IMG;                                            \
    asrc[i] = act + ((h + 1) * PADW + (w + 1)) * 128 + srccol;

#define CONV_KLOOP(WQ)                                                           \
  for (int kk = 0; kk < 9; ++kk) {                                               \
    const int doff = ((kk / 3 - 1) * PADW + (kk % 3 - 1)) * 128;                 \
    __syncthreads();                                                             \
    _Pragma("unroll")                                                            \
    for (int i = 0; i < 4; ++i) async16(asrc[i] + doff, As + ldsoff[i]);         \
    _Pragma("unroll")                                                            \
    for (int i = 0; i < 4; ++i) async16((WQ) + kk * 16384 + boff[i], Bs + ldsoff[i]); \
    __syncthreads();                                                             \
    _Pragma("unroll")                                                            \
    for (int ks = 0; ks < 4; ++ks) {                                             \
      long af[4], bf[4];                                                         \
      _Pragma("unroll")                                                          \
      for (int mi = 0; mi < 4; ++mi)                                             \
        af[mi] = *(const long*)(As + (m_off + mi * 16 + lrow) * 128 + axcol[ks]); \
      _Pragma("unroll")                                                          \
      for (int ni = 0; ni < 4; ++ni)                                             \
        bf[ni] = *(const long*)(Bs + (n_off + ni * 16 + lrow) * 128 + axcol[ks]); \
      _Pragma("unroll")                                                          \
      for (int mi = 0; mi < 4; ++mi)                                             \
        _Pragma("unroll")                                                        \
        for (int ni = 0; ni < 4; ++ni)                                           \
          acc[mi][ni] = __builtin_amdgcn_mfma_f32_16x16x32_fp8_fp8(af[mi], bf[ni], acc[mi][ni], 0, 0, 0); \
    }                                                                            \
  }

// ---------------- conv pass: q?p -> y i16 + stats (used for both convs) ----------------
__global__ __launch_bounds__(256, 3)
void k_conv(const unsigned char* __restrict__ act, const unsigned char* __restrict__ wq,
            short* __restrict__ y, float* __restrict__ stats) {
  __shared__ __align__(16) char smem[33792];
  CONV_SETUP(PCALC_GLOBAL)
  CONV_KLOOP(wq)
  float lsum[4] = {0.f, 0.f, 0.f, 0.f}, lsq[4] = {0.f, 0.f, 0.f, 0.f};
#pragma unroll
  for (int mi = 0; mi < 4; ++mi) {
    int prow = blockIdx.x * 128 + m_off + mi * 16 + quad * 4;
#pragma unroll
    for (int ni = 0; ni < 4; ++ni) {
      int co = n_off + ni * 16 + lrow;
#pragma unroll
      for (int rg = 0; rg < 4; ++rg) {
        float v = acc[mi][ni][rg];        // D: col=lane&15, row=quad*4+rg (verified r6/r7)
        y[(size_t)(prow + rg) * CH + co] = (short)fminf(fmaxf(v, -32767.f), 32767.f);
        lsum[ni] += v; lsq[ni] += v * v;
      }
    }
  }
#pragma unroll
  for (int ni = 0; ni < 4; ++ni) {
    lsum[ni] += __shfl_xor(lsum[ni], 16); lsum[ni] += __shfl_xor(lsum[ni], 32);
    lsq[ni]  += __shfl_xor(lsq[ni], 16);  lsq[ni]  += __shfl_xor(lsq[ni], 32);
  }
  __syncthreads();
  float* red = (float*)(smem + 32768);
  red[tid] = 0.f;
  __syncthreads();
  if (quad == 0) {
#pragma unroll
    for (int ni = 0; ni < 4; ++ni) {
      int co = n_off + ni * 16 + lrow;
      atomicAdd(&red[co], lsum[ni]);
      atomicAdd(&red[CH + co], lsq[ni]);
    }
  }
  __syncthreads();
  atomicAdd(&stats[tid], red[tid]);
}

// ---------------- BN1(inline) + act quant: y i16 -> q2p fp8 padded (+halo zero) ----------------
__global__ void k_bnq(const short* __restrict__ y, const float* __restrict__ stats,
                      const unsigned* __restrict__ abits, const float* __restrict__ g,
                      const float* __restrict__ b, unsigned char* __restrict__ q) {
  __shared__ float bnpS[256];
  int tid = threadIdx.x;
  bn_inline(tid, stats, abits, g, b, bnpS);
  if (blockIdx.x < 64) halo_zero(q + (size_t)blockIdx.x * PADB, tid);
  __syncthreads();
  size_t i = (size_t)blockIdx.x * 256 + tid;           // 8 elems/thread
  short8 v = ((const short8*)y)[i];
  int c0 = (int)((i * 8) & (CH - 1));
  int pix = (int)(i >> 4);
  int n = pix / HWSZ, l = pix - n * HWSZ;
  int h = l / IMG, w = l - h * IMG;
  float t[8];
#pragma unroll
  for (int j = 0; j < 8; ++j) {
    float u = (float)v[j] * bnpS[c0 + j] + bnpS[CH + c0 + j];
    t[j] = rintf(fminf(fmaxf(u, 0.f), 1.f) * 15.f);
  }
  int lo = __builtin_amdgcn_cvt_pk_fp8_f32(t[0], t[1], 0, false);
  lo     = __builtin_amdgcn_cvt_pk_fp8_f32(t[2], t[3], lo, true);
  int hi = __builtin_amdgcn_cvt_pk_fp8_f32(t[4], t[5], 0, false);
  hi     = __builtin_amdgcn_cvt_pk_fp8_f32(t[6], t[7], hi, true);
  *(uint2*)(q + (size_t)n * PADB + ((h + 1) * PADW + (w + 1)) * 128 + c0) =
      (uint2){(unsigned)lo, (unsigned)hi};
}

// ---------------- finale: BN2(inline) + residual, y2 i16 NHWC -> fp32 NCHW ----------------
__global__ void k_fin(const short* __restrict__ y2, const float* __restrict__ stats,
                      const unsigned* __restrict__ abits, const float* __restrict__ g,
                      const float* __restrict__ b, const float* __restrict__ x,
                      float* __restrict__ out, int img0) {
  __shared__ float bnpS[256];
  __shared__ float tile[32][33];
  int tx = threadIdx.x, ty = threadIdx.y, lin = ty * 32 + tx;
  bn_inline(lin, stats, abits, g, b, bnpS);
  __syncthreads();
  int n = img0 + blockIdx.z, p0 = blockIdx.x * 32, c0 = blockIdx.y * 32;
  const short* ys = y2 + (size_t)n * HWSZ * CH;
  float sc = bnpS[c0 + tx], sh = bnpS[CH + c0 + tx];
#pragma unroll
  for (int r = 0; r < 4; ++r) {
    int p = p0 + ty + r * 8;
    tile[ty + r * 8][tx] = (float)ys[(size_t)p * CH + c0 + tx] * sc + sh;  // coalesced along c
  }
  __syncthreads();
  const float* xs = x + ((size_t)n * CH + c0) * HWSZ;
  float*       os = out + ((size_t)n * CH + c0) * HWSZ;
#pragma unroll
  for (int r = 0; r < 4; ++r) {
    int c = ty + r * 8;
    size_t a = (size_t)c * HWSZ + p0 + tx;
    os[a] = tile[tx][c] + xs[a];                       // coalesced along p
  }
}

// ---------------- Plan B only: recompute conv2 for image 63 + BN2 + residual ----------------
__global__ __launch_bounds__(256, 3)
void k_conv_out63(const unsigned char* __restrict__ act, const unsigned char* __restrict__ wq,
                  const float* __restrict__ stats, const unsigned* __restrict__ abits,
                  const float* __restrict__ g, const float* __restrict__ b,
                  const float* __restrict__ x, float* __restrict__ out) {
  __shared__ __align__(16) char smem[33792];
  __shared__ float bnpS[256];
  bn_inline(threadIdx.x, stats, abits, g, b, bnpS);
  CONV_SETUP(PCALC_IMG)
  CONV_KLOOP(wq)
  __syncthreads();
  f16 (*tile)[132] = (f16(*)[132])smem;     // repurpose As/Bs
#pragma unroll
  for (int ni = 0; ni < 4; ++ni) {
    int co = n_off + ni * 16 + lrow;
    float sc = bnpS[co], sh = bnpS[CH + co];
#pragma unroll
    for (int mi = 0; mi < 4; ++mi) {
      int pr = m_off + mi * 16 + quad * 4;
#pragma unroll
      for (int rg = 0; rg < 4; ++rg)
        tile[co][pr + rg] = (f16)(acc[mi][ni][rg] * sc + sh);
    }
  }
  __syncthreads();
  int c = tid >> 1, seg = tid & 1;
  int pl0 = blockIdx.x * 128 + seg * 64;
  if (pl0 < HWSZ) {
    size_t gb = ((size_t)63 * CH + c) * HWSZ + pl0;
    const float* xp = x + gb;
    float* op = out + gb;
    const f16* tr = &tile[c][seg * 64];
#pragma unroll
    for (int j = 0; j < 64; j += 4) {
      f32x4 xv = *(const f32x4*)(xp + j);
      f32x4 ov;
      ov[0] = (float)tr[j]     + xv[0];
      ov[1] = (float)tr[j + 1] + xv[1];
      ov[2] = (float)tr[j + 2] + xv[2];
      ov[3] = (float)tr[j + 3] + xv[3];
      *(f32x4*)(op + j) = ov;
    }
  }
}

extern "C" void kernel_launch(void* const* d_in, const int* in_sizes, int n_in,
                              void* d_out, int out_size, void* d_ws, size_t ws_size,
                              hipStream_t stream) {
  (void)in_sizes; (void)n_in; (void)out_size;
  const float* x  = (const float*)d_in[0];
  const float* w1 = (const float*)d_in[1];
  const float* w2 = (const float*)d_in[2];
  const float* g1 = (const float*)d_in[3];
  const float* b1 = (const float*)d_in[4];
  const float* g2 = (const float*)d_in[5];
  const float* b2 = (const float*)d_in[6];
  float* out = (float*)d_out;

  char* dob = (char*)d_out;
  unsigned char* q1p = (unsigned char*)dob;            // padded fp8 [0, 27.56M)
  unsigned char* q2p = (unsigned char*)dob;            // same region (q1p dead by then)
  short* y1 = (short*)(dob + YOFF);                    // i16 NHWC [27.56M, 78.94M)

  char* ws = (char*)d_ws;
  unsigned* alpha_bits = (unsigned*)ws;
  float* stats1 = (float*)(ws + 256);
  float* stats2 = (float*)(ws + 1280);

  const bool bigws = ws_size >= 51679744u;             // harness-constant branch
  unsigned char *wq1, *wq2;
  short* y2;
  if (bigws) {        // Plan A: everything conflict-free in ws
    wq1 = (unsigned char*)(ws + 4608);
    wq2 = (unsigned char*)(ws + 152064);
    y2  = (short*)(ws + 299520);                       // 51.38 MB -> ws use 51,679,744
  } else {            // Plan B: proven ws budget 582,656 B
    wq1 = (unsigned char*)(dob + WQ1OFF_B);            // dead after conv1
    wq2 = (unsigned char*)(ws + 4608);
    y2  = (short*)(dob + Y2OFF_B);                     // [51.38M, 102.76M)
  }
  unsigned char* q63p = (unsigned char*)(ws + 152064); // Plan B only (430,592 B)

  hipMemsetAsync(ws, 0, 4608, stream);                 // alpha + stats
  k_wmax  <<<64, 256, 0, stream>>>(w1, w2, alpha_bits);
  k_wquant<<<2 * WELEMS / 256, 256, 0, stream>>>(w1, w2, alpha_bits, wq1, wq2);
  k_actq  <<<dim3(98, 4, 64), dim3(32, 8), 0, stream>>>(x, q1p);
  k_conv  <<<NPIX / 128, 256, 0, stream>>>(q1p, wq1, y1, stats1);
  k_bnq   <<<NPIX * CH / 2048, 256, 0, stream>>>(y1, stats1, alpha_bits + 0, g1, b1, q2p);
  k_conv  <<<NPIX / 128, 256, 0, stream>>>(q2p, wq2, y2, stats2);

  if (bigws) {
    // single conflict-free finale over all 64 images
    k_fin <<<dim3(98, 4, 64), dim3(32, 8), 0, stream>>>(y2, stats2, alpha_bits + 1, g2, b2, x, out, 0);
  } else {
    // in-place finale: out[n] destroys y2[2n-64, 2n-63]; batch [a,b] safe iff 2b+2 <= 64+a
    hipMemcpyAsync(q63p, q2p + (size_t)63 * PADB, PADB, hipMemcpyDeviceToDevice, stream);
    k_fin <<<dim3(98, 4, 32), dim3(32, 8), 0, stream>>>(y2, stats2, alpha_bits + 1, g2, b2, x, out, 0);
    k_fin <<<dim3(98, 4, 16), dim3(32, 8), 0, stream>>>(y2, stats2, alpha_bits + 1, g2, b2, x, out, 32);
    k_fin <<<dim3(98, 4,  8), dim3(32, 8), 0, stream>>>(y2, stats2, alpha_bits + 1, g2, b2, x, out, 48);
    k_fin <<<dim3(98, 4,  4), dim3(32, 8), 0, stream>>>(y2, stats2, alpha_bits + 1, g2, b2, x, out, 56);
    k_fin <<<dim3(98, 4,  2), dim3(32, 8), 0, stream>>>(y2, stats2, alpha_bits + 1, g2, b2, x, out, 60);
    k_fin <<<dim3(98, 4,  1), dim3(32, 8), 0, stream>>>(y2, stats2, alpha_bits + 1, g2, b2, x, out, 62);
    k_conv_out63<<<25, 256, 0, stream>>>(q63p, wq2, stats2, alpha_bits + 1, g2, b2, x, out);
  }
}